// Round 11
// baseline (185.833 us; speedup 1.0000x reference)
//
#include <hip/hip_runtime.h>

#define N_NODES 2000
#define NP      2048    // Sp n-dim padding
#define KB      63      // real k-blocks (k = 2000 padded to 2016 in-block)
#define KB3     66      // padded k-blocks: slabs 63..65 of Sp zero-filled (A=0)
#define BATCH   32
#define DIM     64      // DIM_IN == DIM_OUT
#define EMB     16
#define KI      192     // CHEB_K * DIM_IN
#define WCOLS   12288   // DIM_OUT * KI

typedef __bf16 bf16;
typedef __attribute__((ext_vector_type(8))) __bf16 bf16x8;
typedef __attribute__((ext_vector_type(4))) float  f32x4;

struct alignas(8) bf16x4pk { bf16 v[4]; };

// Async global->LDS DMA, 16 B per lane (lane-contiguous within each wave).
__device__ __forceinline__ void gl_lds16(const bf16* g, bf16* l) {
    __builtin_amdgcn_global_load_lds(
        (__attribute__((address_space(1))) void*)(g),
        (__attribute__((address_space(3))) void*)(l), 16, 0, 0);
}

// Packed tile format (4 KB = 256 granules of 16 B) for a 64(row) x 32(k) tile:
//   granule(q, r) = q*64 + r holds elements [row=r][k = q*8 .. q*8+7]
// Fragment read hits 16 consecutive granules per quad-phase -> conflict-free
// ds_read_b128 (R8-R10: SQ_LDS_BANK_CONFLICT == 0).

// ---------------------------------------------------------------------------
// Kernel 1: softmax(relu(nv1@nv2)) row -> Sp packed tiles [kb][nt][q][r][j]
// ---------------------------------------------------------------------------
__global__ __launch_bounds__(256) void adj_softmax_pack(
    const float* __restrict__ nv1, const float* __restrict__ nv2,
    bf16* __restrict__ Sp)
{
    const int row = blockIdx.x;
    const int tid = threadIdx.x;
    const int j0  = tid * 8;
    __shared__ float sa[EMB];
    __shared__ float wred[4];
    __shared__ float bcast;
    if (tid < EMB) sa[tid] = nv1[row * EMB + tid];
    __syncthreads();

    const bool active = (tid < 250);
    float v[8] = {0,0,0,0,0,0,0,0};
    if (active) {
#pragma unroll
        for (int d = 0; d < EMB; ++d) {
            const float sd = sa[d];
            const float4 q0 = *(const float4*)&nv2[d * N_NODES + j0];
            const float4 q1 = *(const float4*)&nv2[d * N_NODES + j0 + 4];
            v[0] += sd * q0.x; v[1] += sd * q0.y; v[2] += sd * q0.z; v[3] += sd * q0.w;
            v[4] += sd * q1.x; v[5] += sd * q1.y; v[6] += sd * q1.z; v[7] += sd * q1.w;
        }
    }
    float lmax = 0.0f;
#pragma unroll
    for (int jj = 0; jj < 8; ++jj) { v[jj] = fmaxf(v[jj], 0.0f); lmax = fmaxf(lmax, v[jj]); }
#pragma unroll
    for (int off = 32; off > 0; off >>= 1)
        lmax = fmaxf(lmax, __shfl_down(lmax, off, 64));
    if ((tid & 63) == 0) wred[tid >> 6] = lmax;
    __syncthreads();
    if (tid == 0) bcast = fmaxf(fmaxf(wred[0], wred[1]), fmaxf(wred[2], wred[3]));
    __syncthreads();
    const float rmax = bcast;

    float lsum = 0.0f;
    if (active) {
#pragma unroll
        for (int jj = 0; jj < 8; ++jj) { v[jj] = __expf(v[jj] - rmax); lsum += v[jj]; }
    }
#pragma unroll
    for (int off = 32; off > 0; off >>= 1)
        lsum += __shfl_down(lsum, off, 64);
    if ((tid & 63) == 0) wred[tid >> 6] = lsum;
    __syncthreads();
    if (tid == 0) bcast = wred[0] + wred[1] + wred[2] + wred[3];
    __syncthreads();
    const float inv = 1.0f / bcast;

    if (tid < 252) {   // threads 250,251 write the k 2000..2015 zero pad
        bf16x8 pk;
#pragma unroll
        for (int jj = 0; jj < 8; ++jj)
            pk[jj] = (bf16)(active ? v[jj] * inv : 0.0f);
        const int kb = j0 >> 5, q = (j0 >> 3) & 3;
        const int nt = row >> 6, r = row & 63;
        *(bf16x8*)&Sp[((size_t)(kb * 32 + nt) * 256 + q * 64 + r) * 8] = pk;
    }
}

// ---------------------------------------------------------------------------
// Kernel 2: x [b][m][c] fp32 -> xTp packed tiles [b][kb][q][c][j] bf16
//           + xbf row-major [b][m][c] bf16.   (b-slab stride = KB3 slabs)
// ---------------------------------------------------------------------------
__global__ __launch_bounds__(256) void transpose_pack_x(
    const float* __restrict__ X, bf16* __restrict__ Xtp, bf16* __restrict__ Xbf)
{
    const int b  = blockIdx.y;
    const int m0 = blockIdx.x * 64;
    const int tid = threadIdx.x;
    __shared__ bf16 T[64][72];
#pragma unroll
    for (int i = 0; i < 4; ++i) {
        int idx = i * 256 + tid;
        int r  = idx >> 4;
        int c4 = (idx & 15) * 4;
        int m  = m0 + r;
        float4 v = make_float4(0.f, 0.f, 0.f, 0.f);
        if (m < N_NODES)
            v = *(const float4*)&X[((size_t)b * N_NODES + m) * DIM + c4];
        bf16x4pk pk;
        pk.v[0] = (bf16)v.x; pk.v[1] = (bf16)v.y;
        pk.v[2] = (bf16)v.z; pk.v[3] = (bf16)v.w;
        if (m < N_NODES)
            *(bf16x4pk*)&Xbf[((size_t)b * N_NODES + m) * DIM + c4] = pk;
        T[c4 + 0][r] = pk.v[0];
        T[c4 + 1][r] = pk.v[1];
        T[c4 + 2][r] = pk.v[2];
        T[c4 + 3][r] = pk.v[3];
    }
    __syncthreads();
#pragma unroll
    for (int i = 0; i < 2; ++i) {
        int idx = i * 256 + tid;       // 0..511
        int c   = idx >> 3;
        int mch = idx & 7;             // 8-elem m-chunk within the 64-m block
        int kb  = (m0 >> 5) + (mch >> 2);
        if (kb < KB) {
            int q = mch & 3;
            bf16x8 vv = *(const bf16x8*)&T[c][mch * 8];
            *(bf16x8*)&Xtp[((size_t)(b * KB3 + kb) * 256 + q * 64 + c) * 8] = vv;
        }
    }
}

// ---------------------------------------------------------------------------
// Kernel 3: spmm — triple-buffered LDS-DMA pipeline with MANUAL partial
// vmcnt waits (AITER pattern: s_waitcnt vmcnt(8), never 0) + raw s_barrier.
// Block = 128n x 128c (2 batches), 4 waves of 64x64. 2-kb stages, 3 buffers
// (96 KB, 1 block/CU, grid = 256 = 1/CU). Issue-to-drain distance = 2 stages.
// Per stage/wave: 16 ds_read_b128, 32 MFMAs, 8 DMA issues.
// ---------------------------------------------------------------------------
__global__ __launch_bounds__(256, 1) void spmm_pack(
    const bf16* __restrict__ Ap, const bf16* __restrict__ Btp,
    bf16* __restrict__ Ybf, bf16* __restrict__ Ytp, int write_ytp)
{
    const int ntB = blockIdx.x;          // 0..15 -> rows ntB*128..+127
    const int bt  = blockIdx.y;          // 0..15 -> batches 2bt, 2bt+1
    const int tid = threadIdx.x;
    const int lane = tid & 63, wave = tid >> 6;
    const int wm = wave >> 1, wn = wave & 1;
    const int l15 = lane & 15, quad = lane >> 4;

    __shared__ bf16 sta[3][2][4096];      // [stage][kbj][128-row granules] 48 KB
    __shared__ bf16 stb[3][2][2][2048];   // [stage][kbj][batch][granules]  48 KB

    const bf16* aslab = Ap  + (size_t)(2 * ntB) * 2048 + tid * 8;   // + kb*65536
    const bf16* b0    = Btp + (size_t)((2 * bt + 0) * KB3) * 2048 + tid * 8;
    const bf16* b1    = Btp + (size_t)((2 * bt + 1) * KB3) * 2048 + tid * 8;

#define DMA_STAGE(st, s_) {                                              \
        _Pragma("unroll")                                                \
        for (int j = 0; j < 2; ++j) {                                    \
            int kbx = (s_) * 2 + j; if (kbx > 65) kbx = 65;              \
            const bf16* pa = aslab + (size_t)kbx * 65536;                \
            gl_lds16(pa,        &sta[st][j][tid * 8]);                   \
            gl_lds16(pa + 2048, &sta[st][j][2048 + tid * 8]);            \
            gl_lds16(b0 + (size_t)kbx * 2048, &stb[st][j][0][tid * 8]);  \
            gl_lds16(b1 + (size_t)kbx * 2048, &stb[st][j][1][tid * 8]);  \
        } }

#define STAGE_COMPUTE(cur, nxt, s_) {                                    \
        asm volatile("s_waitcnt vmcnt(8)" ::: "memory");                 \
        asm volatile("s_barrier" ::: "memory");                          \
        bf16x8 af[2][4], bfr[2][4];                                      \
        _Pragma("unroll")                                                \
        for (int j = 0; j < 2; ++j) {                                    \
            _Pragma("unroll")                                            \
            for (int t = 0; t < 4; ++t)                                  \
                af[j][t] = *(const bf16x8*)&sta[cur][j][wm * 2048 + (quad * 64 + t * 16 + l15) * 8]; \
            _Pragma("unroll")                                            \
            for (int t = 0; t < 4; ++t)                                  \
                bfr[j][t] = *(const bf16x8*)&stb[cur][j][wn][(quad * 64 + t * 16 + l15) * 8]; \
        }                                                                \
        DMA_STAGE(nxt, (s_) + 2);                                        \
        _Pragma("unroll")                                                \
        for (int j = 0; j < 2; ++j)                                      \
            _Pragma("unroll")                                            \
            for (int rt = 0; rt < 4; ++rt)                               \
                _Pragma("unroll")                                        \
                for (int ct = 0; ct < 4; ++ct)                           \
                    acc[rt][ct] = __builtin_amdgcn_mfma_f32_16x16x32_bf16( \
                        af[j][rt], bfr[j][ct], acc[rt][ct], 0, 0, 0);    \
        }

    f32x4 acc[4][4] = {};

    DMA_STAGE(0, 0);
    DMA_STAGE(1, 1);

#pragma unroll 1
    for (int s = 0; s < 33; s += 3) {      // 33 stages = 66 kb
        STAGE_COMPUTE(0, 2, s);
        STAGE_COMPUTE(1, 0, s + 1);
        STAGE_COMPUTE(2, 1, s + 2);
    }
#undef DMA_STAGE
#undef STAGE_COMPUTE

    // Epilogue. C/D layout: col = lane&15, row = quad*4 + reg
    const int n0 = ntB * 128;
    const int b  = 2 * bt + wn;
#pragma unroll
    for (int rt = 0; rt < 4; ++rt) {
        const int nbase = n0 + wm * 64 + rt * 16 + quad * 4;
#pragma unroll
        for (int ct = 0; ct < 4; ++ct) {
            const int c = ct * 16 + l15;
#pragma unroll
            for (int r = 0; r < 4; ++r) {
                int n = nbase + r;
                if (n < N_NODES)
                    Ybf[((size_t)b * N_NODES + n) * DIM + c] = (bf16)acc[rt][ct][r];
            }
            if (write_ytp && nbase + 4 <= N_NODES) {
                const int kb2 = nbase >> 5;
                const int kq  = (nbase & 31) >> 3;
                const int j4  = nbase & 7;       // 0 or 4
                bf16x4pk pk;
                pk.v[0] = (bf16)acc[rt][ct][0];
                pk.v[1] = (bf16)acc[rt][ct][1];
                pk.v[2] = (bf16)acc[rt][ct][2];
                pk.v[3] = (bf16)acc[rt][ct][3];
                *(bf16x4pk*)&Ytp[((size_t)(b * KB3 + kb2) * 256 + kq * 64 + c) * 8 + j4] = pk;
            }
        }
    }
}

// ---------------------------------------------------------------------------
// Kernel 4a: wpT2[col][d] (d pad 32) + embp[n][d] (d pad 32), bf16;
// also zero-fills Sp slabs 63..65 (A=0 makes the 66-slab loop exact;
// B-slab garbage there is finite 0xAA-pattern bf16, 0*B == 0).
// ---------------------------------------------------------------------------
#define Z0   (WCOLS * 32)
#define Z1   (Z0 + N_NODES * 32)
#define Z2   (Z1 + 3 * NP * 32)
__global__ __launch_bounds__(256) void prep_small(
    const float* __restrict__ wp, const float* __restrict__ emb,
    bf16* __restrict__ wpT2, bf16* __restrict__ embp, bf16* __restrict__ Sp63)
{
    int idx = blockIdx.x * 256 + threadIdx.x;
    if (idx < Z0) {
        int col = idx >> 5, d = idx & 31;
        int o  = col / KI;
        int kk = col - o * KI;
        int cheb = kk >> 6, i = kk & 63;
        float v = (d < EMB) ? wp[(((d * 3 + cheb) * 64 + i) * 64) + o] : 0.0f;
        wpT2[idx] = (bf16)v;
    } else if (idx < Z1) {
        int j = idx - Z0;
        int n = j >> 5, d = j & 31;
        float v = (d < EMB) ? emb[n * EMB + d] : 0.0f;
        embp[j] = (bf16)v;
    } else if (idx < Z2) {
        Sp63[idx - Z1] = (bf16)0.0f;
    }
}

// ---------------------------------------------------------------------------
// Kernel 4b: W[n][col] = sum_d embp[n][d] * wpT2[col][d]  (bf16 out)
// ---------------------------------------------------------------------------
__global__ __launch_bounds__(256) void prep_W_mfma(
    const bf16* __restrict__ embp, const bf16* __restrict__ wpT2,
    bf16* __restrict__ W)
{
    const int colbase = blockIdx.x * 256;
    const int n0      = blockIdx.y * 16;
    const int tid  = threadIdx.x;
    const int lane = tid & 63, wave = tid >> 6;
    const int l15 = lane & 15, quad = lane >> 4;

    __shared__ bf16 Cs[16][264];

    const bf16x8 af = *(const bf16x8*)&embp[(n0 + l15) * 32 + quad * 8];
    const f32x4 zero = {};
#pragma unroll
    for (int ct = 0; ct < 4; ++ct) {
        const int col = colbase + wave * 64 + ct * 16 + l15;
        bf16x8 bfr = *(const bf16x8*)&wpT2[(size_t)col * 32 + quad * 8];
        f32x4 acc = __builtin_amdgcn_mfma_f32_16x16x32_bf16(af, bfr, zero, 0, 0, 0);
#pragma unroll
        for (int r = 0; r < 4; ++r)
            Cs[quad * 4 + r][wave * 64 + ct * 16 + l15] = (bf16)acc[r];
    }
    __syncthreads();
    {
        const int row = tid >> 4;
        const int c16 = (tid & 15) * 16;
        bf16x8 v0 = *(const bf16x8*)&Cs[row][c16];
        bf16x8 v1 = *(const bf16x8*)&Cs[row][c16 + 8];
        bf16* dst = &W[(size_t)(n0 + row) * WCOLS + colbase + c16];
        *(bf16x8*)dst       = v0;
        *(bf16x8*)(dst + 8) = v1;
    }
}

// ---------------------------------------------------------------------------
// Kernel 5: per-node combine (bf16 inputs).
// ---------------------------------------------------------------------------
__global__ __launch_bounds__(256) void combine_node(
    const bf16* __restrict__ xbf, const bf16* __restrict__ y1bf,
    const bf16* __restrict__ y2bf, const float* __restrict__ emb,
    const float* __restrict__ bp, const bf16* __restrict__ W,
    float* __restrict__ out)
{
    const int n   = blockIdx.x;
    const int tid = threadIdx.x;
    const int lane = tid & 63, wave = tid >> 6;
    const int l15 = lane & 15, quad = lane >> 4;

    __shared__ bf16 As[BATCH][200];
    __shared__ bf16 Ws[DIM][200];
    __shared__ float bias_s[DIM];
    __shared__ float emb_s[EMB];

    if (tid < EMB) emb_s[tid] = emb[n * EMB + tid];

    {
        const int b  = tid >> 3;
        const int c8 = (tid & 7) * 8;
        const size_t base = ((size_t)b * N_NODES + n) * DIM + c8;
        bf16x8 vx = *(const bf16x8*)&xbf [base];
        bf16x8 v1 = *(const bf16x8*)&y1bf[base];
        bf16x8 v2 = *(const bf16x8*)&y2bf[base];
        bf16x8 p2;
#pragma unroll
        for (int e = 0; e < 8; ++e)
            p2[e] = (bf16)(2.0f * (float)v2[e] - (float)vx[e]);
        *(bf16x8*)&As[b][c8]       = vx;
        *(bf16x8*)&As[b][64 + c8]  = v1;
        *(bf16x8*)&As[b][128 + c8] = p2;
    }
    {
        const bf16* Wn = W + (size_t)n * WCOLS;
#pragma unroll
        for (int jj = 0; jj < 6; ++jj) {
            int chunk = jj * 256 + tid;
            int o  = chunk / 24;
            int kc = chunk - o * 24;
            bf16x8 v = *(const bf16x8*)&Wn[(size_t)chunk * 8];
            *(bf16x8*)&Ws[o][kc * 8] = v;
        }
    }
    __syncthreads();

    if (tid < DIM) {
        float s = 0.0f;
#pragma unroll
        for (int d = 0; d < EMB; ++d) s += emb_s[d] * bp[d * DIM + tid];
        bias_s[tid] = s;
    }

    bf16x8 af[2][6];
#pragma unroll
    for (int mt = 0; mt < 2; ++mt)
#pragma unroll
        for (int ks = 0; ks < 6; ++ks)
            af[mt][ks] = *(const bf16x8*)&As[mt * 16 + l15][ks * 32 + quad * 8];

    f32x4 acc[2] = {};
#pragma unroll
    for (int ks = 0; ks < 6; ++ks) {
        bf16x8 bfr = *(const bf16x8*)&Ws[wave * 16 + l15][ks * 32 + quad * 8];
        acc[0] = __builtin_amdgcn_mfma_f32_16x16x32_bf16(af[0][ks], bfr, acc[0], 0, 0, 0);
        acc[1] = __builtin_amdgcn_mfma_f32_16x16x32_bf16(af[1][ks], bfr, acc[1], 0, 0, 0);
    }
    __syncthreads();

    const int o = wave * 16 + l15;
    const float bv = bias_s[o];
#pragma unroll
    for (int mt = 0; mt < 2; ++mt)
#pragma unroll
        for (int r = 0; r < 4; ++r) {
            int b = mt * 16 + quad * 4 + r;
            out[((size_t)b * N_NODES + n) * DIM + o] = acc[mt][r] + bv;
        }
}

// ---------------------------------------------------------------------------
extern "C" void kernel_launch(void* const* d_in, const int* in_sizes, int n_in,
                              void* d_out, int out_size, void* d_ws, size_t ws_size,
                              hipStream_t stream) {
    const float* x   = (const float*)d_in[0];  // [32,2000,64]
    const float* emb = (const float*)d_in[1];  // [2000,16]
    const float* nv1 = (const float*)d_in[2];  // [2000,16]
    const float* nv2 = (const float*)d_in[3];  // [16,2000]
    const float* wp  = (const float*)d_in[4];  // [16,3,64,64]
    const float* bp  = (const float*)d_in[5];  // [16,64]
    float* out = (float*)d_out;                // [32,2000,64]

    char* w = (char*)d_ws;
    bf16* Sp   = (bf16*)w;  w += (size_t)KB3 * NP * 32 * 2;           //  8.65 MB
    bf16* xTp  = (bf16*)w;  w += (size_t)BATCH * KB3 * DIM * 32 * 2;  //  8.65 MB
    bf16* y1Tp = (bf16*)w;  w += (size_t)BATCH * KB3 * DIM * 32 * 2;  //  8.65 MB
    bf16* xbf  = (bf16*)w;  w += (size_t)BATCH * N_NODES * DIM * 2;   //  8.19 MB
    bf16* y1bf = (bf16*)w;  w += (size_t)BATCH * N_NODES * DIM * 2;   //  8.19 MB
    bf16* y2bf = (bf16*)w;  w += (size_t)BATCH * N_NODES * DIM * 2;   //  8.19 MB
    bf16* wpT2 = (bf16*)w;  w += (size_t)WCOLS * 32 * 2;              //  0.79 MB
    bf16* embp = (bf16*)w;  w += (size_t)N_NODES * 32 * 2;            //  0.13 MB
    bf16* W    = (bf16*)w;                                            // 49.15 MB

    adj_softmax_pack<<<N_NODES, 256, 0, stream>>>(nv1, nv2, Sp);
    transpose_pack_x<<<dim3(32, BATCH), 256, 0, stream>>>(x, xTp, xbf);
    prep_small<<<(Z2 + 255) / 256, 256, 0, stream>>>(
        wp, emb, wpT2, embp, Sp + (size_t)63 * NP * 32);
    prep_W_mfma<<<dim3(WCOLS / 256, N_NODES / 16), 256, 0, stream>>>(embp, wpT2, W);
    spmm_pack<<<dim3(16, 16), 256, 0, stream>>>(Sp, xTp,  y1bf, y1Tp, 1);
    spmm_pack<<<dim3(16, 16), 256, 0, stream>>>(Sp, y1Tp, y2bf, y1Tp, 0);
    combine_node<<<N_NODES, 256, 0, stream>>>(xbf, y1bf, y2bf, emb, bp, W, out);
}

// Round 12
// 178.906 us; speedup vs baseline: 1.0387x; 1.0387x over previous
//
#include <hip/hip_runtime.h>

#define N_NODES 2000
#define NP      2048    // Sp n-dim padding
#define KB      63      // real k-blocks (k = 2000 padded to 2016 in-block)
#define KB3     66      // padded k-blocks: slabs 63..65 of Sp zero-filled (A=0)
#define BATCH   32
#define DIM     64      // DIM_IN == DIM_OUT
#define EMB     16
#define KI      192     // CHEB_K * DIM_IN
#define WCOLS   12288   // DIM_OUT * KI

typedef __bf16 bf16;
typedef __attribute__((ext_vector_type(8))) __bf16 bf16x8;
typedef __attribute__((ext_vector_type(4))) float  f32x4;

struct alignas(8) bf16x4pk { bf16 v[4]; };

// Async global->LDS DMA, 16 B per lane (lane-contiguous within each wave).
__device__ __forceinline__ void gl_lds16(const bf16* g, bf16* l) {
    __builtin_amdgcn_global_load_lds(
        (__attribute__((address_space(1))) void*)(g),
        (__attribute__((address_space(3))) void*)(l), 16, 0, 0);
}

// Packed tile format (4 KB = 256 granules of 16 B) for a 64(row) x 32(k) tile:
//   granule(q, r) = q*64 + r holds elements [row=r][k = q*8 .. q*8+7]
// Fragment read hits 16 consecutive granules per quad-phase -> conflict-free
// ds_read_b128 (R8-R11: SQ_LDS_BANK_CONFLICT == 0).

// ---------------------------------------------------------------------------
// Kernel 1: softmax(relu(nv1@nv2)) row -> Sp packed tiles [kb][nt][q][r][j]
// ---------------------------------------------------------------------------
__global__ __launch_bounds__(256) void adj_softmax_pack(
    const float* __restrict__ nv1, const float* __restrict__ nv2,
    bf16* __restrict__ Sp)
{
    const int row = blockIdx.x;
    const int tid = threadIdx.x;
    const int j0  = tid * 8;
    __shared__ float sa[EMB];
    __shared__ float wred[4];
    __shared__ float bcast;
    if (tid < EMB) sa[tid] = nv1[row * EMB + tid];
    __syncthreads();

    const bool active = (tid < 250);
    float v[8] = {0,0,0,0,0,0,0,0};
    if (active) {
#pragma unroll
        for (int d = 0; d < EMB; ++d) {
            const float sd = sa[d];
            const float4 q0 = *(const float4*)&nv2[d * N_NODES + j0];
            const float4 q1 = *(const float4*)&nv2[d * N_NODES + j0 + 4];
            v[0] += sd * q0.x; v[1] += sd * q0.y; v[2] += sd * q0.z; v[3] += sd * q0.w;
            v[4] += sd * q1.x; v[5] += sd * q1.y; v[6] += sd * q1.z; v[7] += sd * q1.w;
        }
    }
    float lmax = 0.0f;
#pragma unroll
    for (int jj = 0; jj < 8; ++jj) { v[jj] = fmaxf(v[jj], 0.0f); lmax = fmaxf(lmax, v[jj]); }
#pragma unroll
    for (int off = 32; off > 0; off >>= 1)
        lmax = fmaxf(lmax, __shfl_down(lmax, off, 64));
    if ((tid & 63) == 0) wred[tid >> 6] = lmax;
    __syncthreads();
    if (tid == 0) bcast = fmaxf(fmaxf(wred[0], wred[1]), fmaxf(wred[2], wred[3]));
    __syncthreads();
    const float rmax = bcast;

    float lsum = 0.0f;
    if (active) {
#pragma unroll
        for (int jj = 0; jj < 8; ++jj) { v[jj] = __expf(v[jj] - rmax); lsum += v[jj]; }
    }
#pragma unroll
    for (int off = 32; off > 0; off >>= 1)
        lsum += __shfl_down(lsum, off, 64);
    if ((tid & 63) == 0) wred[tid >> 6] = lsum;
    __syncthreads();
    if (tid == 0) bcast = wred[0] + wred[1] + wred[2] + wred[3];
    __syncthreads();
    const float inv = 1.0f / bcast;

    if (tid < 252) {   // threads 250,251 write the k 2000..2015 zero pad
        bf16x8 pk;
#pragma unroll
        for (int jj = 0; jj < 8; ++jj)
            pk[jj] = (bf16)(active ? v[jj] * inv : 0.0f);
        const int kb = j0 >> 5, q = (j0 >> 3) & 3;
        const int nt = row >> 6, r = row & 63;
        *(bf16x8*)&Sp[((size_t)(kb * 32 + nt) * 256 + q * 64 + r) * 8] = pk;
    }
}

// ---------------------------------------------------------------------------
// Kernel 2: x [b][m][c] fp32 -> xTp packed tiles [b][kb][q][c][j] bf16
//           + xbf row-major [b][m][c] bf16.   (b-slab stride = KB3 slabs)
// ---------------------------------------------------------------------------
__global__ __launch_bounds__(256) void transpose_pack_x(
    const float* __restrict__ X, bf16* __restrict__ Xtp, bf16* __restrict__ Xbf)
{
    const int b  = blockIdx.y;
    const int m0 = blockIdx.x * 64;
    const int tid = threadIdx.x;
    __shared__ bf16 T[64][72];
#pragma unroll
    for (int i = 0; i < 4; ++i) {
        int idx = i * 256 + tid;
        int r  = idx >> 4;
        int c4 = (idx & 15) * 4;
        int m  = m0 + r;
        float4 v = make_float4(0.f, 0.f, 0.f, 0.f);
        if (m < N_NODES)
            v = *(const float4*)&X[((size_t)b * N_NODES + m) * DIM + c4];
        bf16x4pk pk;
        pk.v[0] = (bf16)v.x; pk.v[1] = (bf16)v.y;
        pk.v[2] = (bf16)v.z; pk.v[3] = (bf16)v.w;
        if (m < N_NODES)
            *(bf16x4pk*)&Xbf[((size_t)b * N_NODES + m) * DIM + c4] = pk;
        T[c4 + 0][r] = pk.v[0];
        T[c4 + 1][r] = pk.v[1];
        T[c4 + 2][r] = pk.v[2];
        T[c4 + 3][r] = pk.v[3];
    }
    __syncthreads();
#pragma unroll
    for (int i = 0; i < 2; ++i) {
        int idx = i * 256 + tid;       // 0..511
        int c   = idx >> 3;
        int mch = idx & 7;             // 8-elem m-chunk within the 64-m block
        int kb  = (m0 >> 5) + (mch >> 2);
        if (kb < KB) {
            int q = mch & 3;
            bf16x8 vv = *(const bf16x8*)&T[c][mch * 8];
            *(bf16x8*)&Xtp[((size_t)(b * KB3 + kb) * 256 + q * 64 + c) * 8] = vv;
        }
    }
}

// ---------------------------------------------------------------------------
// Kernel 3: spmm — R10's proven geometry (128n x 64c block, 4 waves of
// 32n x 64c, 512 blocks = 2/CU) with TRIPLE-buffered 2-kb stages and manual
// partial waits: s_waitcnt vmcnt(6) drains only the current stage, leaving
// the next stage's 6 DMAs in flight (issue-to-drain = ~2 stages). R11
// showed the technique at 1 block/CU regresses; this isolates occupancy.
// LDS: 3 x (16 KB A + 8 KB B) = 72 KB (same as R10).
// ---------------------------------------------------------------------------
__global__ __launch_bounds__(256, 2) void spmm_pack(
    const bf16* __restrict__ Ap, const bf16* __restrict__ Btp,
    bf16* __restrict__ Ybf, bf16* __restrict__ Ytp, int write_ytp)
{
    const int ntB = blockIdx.x;          // 0..15 (fastest -> XCD = ntB % 8)
    const int b   = blockIdx.y;          // 0..31
    const int n0  = ntB * 128;
    const int tid = threadIdx.x;
    const int lane = tid & 63, wave = tid >> 6;
    const int l15 = lane & 15, quad = lane >> 4;

    __shared__ bf16 As[3][2][4096];   // [stage][kbj][128 rows x 32 k]  48 KB
    __shared__ bf16 Bs[3][2][2048];   // [stage][kbj][ 64 c   x 32 k]  24 KB

    const bf16* aslab = Ap  + (size_t)(ntB * 2) * 2048 + tid * 8;  // + kb*65536
    const bf16* bslab = Btp + (size_t)(b * KB3) * 2048 + tid * 8;  // + kb*2048

#define DMA_STAGE(st, s_) {                                           \
        _Pragma("unroll")                                             \
        for (int j = 0; j < 2; ++j) {                                 \
            int kbx = (s_) * 2 + j; if (kbx > 65) kbx = 65;           \
            const bf16* pa = aslab + (size_t)kbx * (32 * 2048);       \
            const bf16* pb = bslab + (size_t)kbx * 2048;              \
            gl_lds16(pa,        &As[st][j][tid * 8]);                 \
            gl_lds16(pa + 2048, &As[st][j][2048 + tid * 8]);          \
            gl_lds16(pb,        &Bs[st][j][tid * 8]);  } }

    f32x4 acc[2][4] = {};
    const int ga = (wave >> 1) * 256 + quad * 64 + (wave & 1) * 32; // A granule base
    const int gb = quad * 64;                                       // B granule base

#define STAGE(cur, s_) {                                              \
        asm volatile("s_waitcnt vmcnt(6)" ::: "memory");              \
        asm volatile("s_barrier" ::: "memory");                       \
        bf16x8 af[2][2], bfr[2][4];                                   \
        _Pragma("unroll")                                             \
        for (int j = 0; j < 2; ++j) {                                 \
            _Pragma("unroll")                                         \
            for (int t = 0; t < 2; ++t)                               \
                af[j][t] = *(const bf16x8*)&As[cur][j][(ga + t * 16 + l15) * 8]; \
            _Pragma("unroll")                                         \
            for (int t = 0; t < 4; ++t)                               \
                bfr[j][t] = *(const bf16x8*)&Bs[cur][j][(gb + t * 16 + l15) * 8]; \
        }                                                             \
        DMA_STAGE((cur + 2) % 3, (s_) + 2);                           \
        _Pragma("unroll")                                             \
        for (int j = 0; j < 2; ++j)                                   \
          _Pragma("unroll")                                           \
          for (int rt = 0; rt < 2; ++rt)                              \
            _Pragma("unroll")                                         \
            for (int ct = 0; ct < 4; ++ct)                            \
                acc[rt][ct] = __builtin_amdgcn_mfma_f32_16x16x32_bf16(\
                    af[j][rt], bfr[j][ct], acc[rt][ct], 0, 0, 0);     \
        }

    DMA_STAGE(0, 0);
    DMA_STAGE(1, 1);
#pragma unroll 1
    for (int s = 0; s < 33; s += 3) {      // 33 stages x 2 kb = 66 kb
        STAGE(0, s);
        STAGE(1, s + 1);
        STAGE(2, s + 2);
    }
#undef DMA_STAGE
#undef STAGE

    // Epilogue. C/D layout: col = lane&15, row = quad*4 + reg
#pragma unroll
    for (int rt = 0; rt < 2; ++rt) {
        const int nbase = n0 + wave * 32 + rt * 16 + quad * 4;
#pragma unroll
        for (int ct = 0; ct < 4; ++ct) {
            const int c = ct * 16 + l15;
#pragma unroll
            for (int r = 0; r < 4; ++r) {
                int n = nbase + r;
                if (n < N_NODES)
                    Ybf[((size_t)b * N_NODES + n) * DIM + c] = (bf16)acc[rt][ct][r];
            }
            if (write_ytp && nbase + 4 <= N_NODES) {
                const int kb2 = nbase >> 5;
                const int kq  = (nbase & 31) >> 3;
                const int j4  = nbase & 7;       // 0 or 4
                bf16x4pk pk;
                pk.v[0] = (bf16)acc[rt][ct][0];
                pk.v[1] = (bf16)acc[rt][ct][1];
                pk.v[2] = (bf16)acc[rt][ct][2];
                pk.v[3] = (bf16)acc[rt][ct][3];
                *(bf16x4pk*)&Ytp[((size_t)(b * KB3 + kb2) * 256 + kq * 64 + c) * 8 + j4] = pk;
            }
        }
    }
}

// ---------------------------------------------------------------------------
// Kernel 4a: wpT2[col][d] (d pad 32) + embp[n][d] (d pad 32), bf16;
// also zero-fills Sp slabs 63..65 (A=0 makes the 66-slab loop exact;
// B-slab garbage there is finite 0xAA-pattern bf16, 0*B == 0).
// ---------------------------------------------------------------------------
#define Z0   (WCOLS * 32)
#define Z1   (Z0 + N_NODES * 32)
#define Z2   (Z1 + 3 * NP * 32)
__global__ __launch_bounds__(256) void prep_small(
    const float* __restrict__ wp, const float* __restrict__ emb,
    bf16* __restrict__ wpT2, bf16* __restrict__ embp, bf16* __restrict__ Sp63)
{
    int idx = blockIdx.x * 256 + threadIdx.x;
    if (idx < Z0) {
        int col = idx >> 5, d = idx & 31;
        int o  = col / KI;
        int kk = col - o * KI;
        int cheb = kk >> 6, i = kk & 63;
        float v = (d < EMB) ? wp[(((d * 3 + cheb) * 64 + i) * 64) + o] : 0.0f;
        wpT2[idx] = (bf16)v;
    } else if (idx < Z1) {
        int j = idx - Z0;
        int n = j >> 5, d = j & 31;
        float v = (d < EMB) ? emb[n * EMB + d] : 0.0f;
        embp[j] = (bf16)v;
    } else if (idx < Z2) {
        Sp63[idx - Z1] = (bf16)0.0f;
    }
}

// ---------------------------------------------------------------------------
// Kernel 4b: W[n][col] = sum_d embp[n][d] * wpT2[col][d]  (bf16 out)
// ---------------------------------------------------------------------------
__global__ __launch_bounds__(256) void prep_W_mfma(
    const bf16* __restrict__ embp, const bf16* __restrict__ wpT2,
    bf16* __restrict__ W)
{
    const int colbase = blockIdx.x * 256;
    const int n0      = blockIdx.y * 16;
    const int tid  = threadIdx.x;
    const int lane = tid & 63, wave = tid >> 6;
    const int l15 = lane & 15, quad = lane >> 4;

    __shared__ bf16 Cs[16][264];

    const bf16x8 af = *(const bf16x8*)&embp[(n0 + l15) * 32 + quad * 8];
    const f32x4 zero = {};
#pragma unroll
    for (int ct = 0; ct < 4; ++ct) {
        const int col = colbase + wave * 64 + ct * 16 + l15;
        bf16x8 bfr = *(const bf16x8*)&wpT2[(size_t)col * 32 + quad * 8];
        f32x4 acc = __builtin_amdgcn_mfma_f32_16x16x32_bf16(af, bfr, zero, 0, 0, 0);
#pragma unroll
        for (int r = 0; r < 4; ++r)
            Cs[quad * 4 + r][wave * 64 + ct * 16 + l15] = (bf16)acc[r];
    }
    __syncthreads();
    {
        const int row = tid >> 4;
        const int c16 = (tid & 15) * 16;
        bf16x8 v0 = *(const bf16x8*)&Cs[row][c16];
        bf16x8 v1 = *(const bf16x8*)&Cs[row][c16 + 8];
        bf16* dst = &W[(size_t)(n0 + row) * WCOLS + colbase + c16];
        *(bf16x8*)dst       = v0;
        *(bf16x8*)(dst + 8) = v1;
    }
}

// ---------------------------------------------------------------------------
// Kernel 5: per-node combine (bf16 inputs).
// ---------------------------------------------------------------------------
__global__ __launch_bounds__(256) void combine_node(
    const bf16* __restrict__ xbf, const bf16* __restrict__ y1bf,
    const bf16* __restrict__ y2bf, const float* __restrict__ emb,
    const float* __restrict__ bp, const bf16* __restrict__ W,
    float* __restrict__ out)
{
    const int n   = blockIdx.x;
    const int tid = threadIdx.x;
    const int lane = tid & 63, wave = tid >> 6;
    const int l15 = lane & 15, quad = lane >> 4;

    __shared__ bf16 As[BATCH][200];
    __shared__ bf16 Ws[DIM][200];
    __shared__ float bias_s[DIM];
    __shared__ float emb_s[EMB];

    if (tid < EMB) emb_s[tid] = emb[n * EMB + tid];

    {
        const int b  = tid >> 3;
        const int c8 = (tid & 7) * 8;
        const size_t base = ((size_t)b * N_NODES + n) * DIM + c8;
        bf16x8 vx = *(const bf16x8*)&xbf [base];
        bf16x8 v1 = *(const bf16x8*)&y1bf[base];
        bf16x8 v2 = *(const bf16x8*)&y2bf[base];
        bf16x8 p2;
#pragma unroll
        for (int e = 0; e < 8; ++e)
            p2[e] = (bf16)(2.0f * (float)v2[e] - (float)vx[e]);
        *(bf16x8*)&As[b][c8]       = vx;
        *(bf16x8*)&As[b][64 + c8]  = v1;
        *(bf16x8*)&As[b][128 + c8] = p2;
    }
    {
        const bf16* Wn = W + (size_t)n * WCOLS;
#pragma unroll
        for (int jj = 0; jj < 6; ++jj) {
            int chunk = jj * 256 + tid;
            int o  = chunk / 24;
            int kc = chunk - o * 24;
            bf16x8 v = *(const bf16x8*)&Wn[(size_t)chunk * 8];
            *(bf16x8*)&Ws[o][kc * 8] = v;
        }
    }
    __syncthreads();

    if (tid < DIM) {
        float s = 0.0f;
#pragma unroll
        for (int d = 0; d < EMB; ++d) s += emb_s[d] * bp[d * DIM + tid];
        bias_s[tid] = s;
    }

    bf16x8 af[2][6];
#pragma unroll
    for (int mt = 0; mt < 2; ++mt)
#pragma unroll
        for (int ks = 0; ks < 6; ++ks)
            af[mt][ks] = *(const bf16x8*)&As[mt * 16 + l15][ks * 32 + quad * 8];

    f32x4 acc[2] = {};
#pragma unroll
    for (int ks = 0; ks < 6; ++ks) {
        bf16x8 bfr = *(const bf16x8*)&Ws[wave * 16 + l15][ks * 32 + quad * 8];
        acc[0] = __builtin_amdgcn_mfma_f32_16x16x32_bf16(af[0][ks], bfr, acc[0], 0, 0, 0);
        acc[1] = __builtin_amdgcn_mfma_f32_16x16x32_bf16(af[1][ks], bfr, acc[1], 0, 0, 0);
    }
    __syncthreads();

    const int o = wave * 16 + l15;
    const float bv = bias_s[o];
#pragma unroll
    for (int mt = 0; mt < 2; ++mt)
#pragma unroll
        for (int r = 0; r < 4; ++r) {
            int b = mt * 16 + quad * 4 + r;
            out[((size_t)b * N_NODES + n) * DIM + o] = acc[mt][r] + bv;
        }
}

// ---------------------------------------------------------------------------
extern "C" void kernel_launch(void* const* d_in, const int* in_sizes, int n_in,
                              void* d_out, int out_size, void* d_ws, size_t ws_size,
                              hipStream_t stream) {
    const float* x   = (const float*)d_in[0];  // [32,2000,64]
    const float* emb = (const float*)d_in[1];  // [2000,16]
    const float* nv1 = (const float*)d_in[2];  // [2000,16]
    const float* nv2 = (const float*)d_in[3];  // [16,2000]
    const float* wp  = (const float*)d_in[4];  // [16,3,64,64]
    const float* bp  = (const float*)d_in[5];  // [16,64]
    float* out = (float*)d_out;                // [32,2000,64]

    char* w = (char*)d_ws;
    bf16* Sp   = (bf16*)w;  w += (size_t)KB3 * NP * 32 * 2;           //  8.65 MB
    bf16* xTp  = (bf16*)w;  w += (size_t)BATCH * KB3 * DIM * 32 * 2;  //  8.65 MB
    bf16* y1Tp = (bf16*)w;  w += (size_t)BATCH * KB3 * DIM * 32 * 2;  //  8.65 MB
    bf16* xbf  = (bf16*)w;  w += (size_t)BATCH * N_NODES * DIM * 2;   //  8.19 MB
    bf16* y1bf = (bf16*)w;  w += (size_t)BATCH * N_NODES * DIM * 2;   //  8.19 MB
    bf16* y2bf = (bf16*)w;  w += (size_t)BATCH * N_NODES * DIM * 2;   //  8.19 MB
    bf16* wpT2 = (bf16*)w;  w += (size_t)WCOLS * 32 * 2;              //  0.79 MB
    bf16* embp = (bf16*)w;  w += (size_t)N_NODES * 32 * 2;            //  0.13 MB
    bf16* W    = (bf16*)w;                                            // 49.15 MB

    adj_softmax_pack<<<N_NODES, 256, 0, stream>>>(nv1, nv2, Sp);
    transpose_pack_x<<<dim3(32, BATCH), 256, 0, stream>>>(x, xTp, xbf);
    prep_small<<<(Z2 + 255) / 256, 256, 0, stream>>>(
        wp, emb, wpT2, embp, Sp + (size_t)63 * NP * 32);
    prep_W_mfma<<<dim3(WCOLS / 256, N_NODES / 16), 256, 0, stream>>>(embp, wpT2, W);
    spmm_pack<<<dim3(16, BATCH), 256, 0, stream>>>(Sp, xTp,  y1bf, y1Tp, 1);
    spmm_pack<<<dim3(16, BATCH), 256, 0, stream>>>(Sp, y1Tp, y2bf, y1Tp, 0);
    combine_node<<<N_NODES, 256, 0, stream>>>(xbf, y1bf, y2bf, emb, bp, W, out);
}

// Round 13
// 170.080 us; speedup vs baseline: 1.0926x; 1.0519x over previous
//
#include <hip/hip_runtime.h>

#define N_NODES 2000
#define NP      2048    // Sp n-dim padding
#define KB      63      // real k-blocks (k = 2000 padded to 2016 in-block)
#define KB3     66      // padded k-blocks: slabs 63..65 of Sp zero-filled (A=0)
#define BATCH   32
#define DIM     64      // DIM_IN == DIM_OUT
#define EMB     16
#define KI      192     // CHEB_K * DIM_IN
#define WCOLS   12288   // DIM_OUT * KI

typedef __bf16 bf16;
typedef __attribute__((ext_vector_type(8))) __bf16 bf16x8;
typedef __attribute__((ext_vector_type(4))) float  f32x4;

struct alignas(8) bf16x4pk { bf16 v[4]; };

// Async global->LDS DMA, 16 B per lane (lane-contiguous within each wave).
__device__ __forceinline__ void gl_lds16(const bf16* g, bf16* l) {
    __builtin_amdgcn_global_load_lds(
        (__attribute__((address_space(1))) void*)(g),
        (__attribute__((address_space(3))) void*)(l), 16, 0, 0);
}

// Packed tile format (4 KB = 256 granules of 16 B) for a 64(row) x 32(k) tile:
//   granule(q, r) = q*64 + r holds elements [row=r][k = q*8 .. q*8+7]
// Fragment read hits 16 consecutive granules per quad-phase -> conflict-free
// ds_read_b128 (R8-R12: SQ_LDS_BANK_CONFLICT == 0).

#define Z0   (WCOLS * 32)
#define Z1   (Z0 + N_NODES * 32)
#define Z2   (Z1 + 3 * NP * 32)
// fused-prep grid: [0,2000) softmax rows | [2000,3024) transpose tiles |
// [3024, 3024+2554) prep_small chunks  (Z2/256 == 2554 exactly)
#define PREP_SM_BLK   2554
#define PREP_BLOCKS   (N_NODES + 1024 + PREP_SM_BLK)

// ---------------------------------------------------------------------------
// Kernel A (fused): softmax -> Sp packed | x transpose-pack | wpT2/embp/zero
// All three phases depend only on kernel inputs; fusing cuts 2 launch gaps.
// ---------------------------------------------------------------------------
__global__ __launch_bounds__(256) void prep_fused(
    const float* __restrict__ nv1, const float* __restrict__ nv2,
    bf16* __restrict__ Sp,
    const float* __restrict__ X, bf16* __restrict__ Xtp, bf16* __restrict__ Xbf,
    const float* __restrict__ wp, const float* __restrict__ emb,
    bf16* __restrict__ wpT2, bf16* __restrict__ embp, bf16* __restrict__ Sp63)
{
    const int bid = blockIdx.x;
    const int tid = threadIdx.x;

    if (bid < N_NODES) {
        // ----- softmax(relu(nv1@nv2)) row -> packed Sp tiles -----
        const int row = bid;
        const int j0  = tid * 8;
        __shared__ float sa[EMB];
        __shared__ float wred[4];
        __shared__ float bcast;
        if (tid < EMB) sa[tid] = nv1[row * EMB + tid];
        __syncthreads();

        const bool active = (tid < 250);
        float v[8] = {0,0,0,0,0,0,0,0};
        if (active) {
#pragma unroll
            for (int d = 0; d < EMB; ++d) {
                const float sd = sa[d];
                const float4 q0 = *(const float4*)&nv2[d * N_NODES + j0];
                const float4 q1 = *(const float4*)&nv2[d * N_NODES + j0 + 4];
                v[0] += sd * q0.x; v[1] += sd * q0.y; v[2] += sd * q0.z; v[3] += sd * q0.w;
                v[4] += sd * q1.x; v[5] += sd * q1.y; v[6] += sd * q1.z; v[7] += sd * q1.w;
            }
        }
        float lmax = 0.0f;
#pragma unroll
        for (int jj = 0; jj < 8; ++jj) { v[jj] = fmaxf(v[jj], 0.0f); lmax = fmaxf(lmax, v[jj]); }
#pragma unroll
        for (int off = 32; off > 0; off >>= 1)
            lmax = fmaxf(lmax, __shfl_down(lmax, off, 64));
        if ((tid & 63) == 0) wred[tid >> 6] = lmax;
        __syncthreads();
        if (tid == 0) bcast = fmaxf(fmaxf(wred[0], wred[1]), fmaxf(wred[2], wred[3]));
        __syncthreads();
        const float rmax = bcast;

        float lsum = 0.0f;
        if (active) {
#pragma unroll
            for (int jj = 0; jj < 8; ++jj) { v[jj] = __expf(v[jj] - rmax); lsum += v[jj]; }
        }
#pragma unroll
        for (int off = 32; off > 0; off >>= 1)
            lsum += __shfl_down(lsum, off, 64);
        if ((tid & 63) == 0) wred[tid >> 6] = lsum;
        __syncthreads();
        if (tid == 0) bcast = wred[0] + wred[1] + wred[2] + wred[3];
        __syncthreads();
        const float inv = 1.0f / bcast;

        if (tid < 252) {   // threads 250,251 write the k 2000..2015 zero pad
            bf16x8 pk;
#pragma unroll
            for (int jj = 0; jj < 8; ++jj)
                pk[jj] = (bf16)(active ? v[jj] * inv : 0.0f);
            const int kb = j0 >> 5, q = (j0 >> 3) & 3;
            const int nt = row >> 6, r = row & 63;
            *(bf16x8*)&Sp[((size_t)(kb * 32 + nt) * 256 + q * 64 + r) * 8] = pk;
        }
    } else if (bid < N_NODES + 1024) {
        // ----- x [b][m][c] fp32 -> xTp packed + xbf row-major bf16 -----
        const int t  = bid - N_NODES;
        const int b  = t >> 5;
        const int m0 = (t & 31) * 64;
        __shared__ bf16 T[64][72];
#pragma unroll
        for (int i = 0; i < 4; ++i) {
            int idx = i * 256 + tid;
            int r  = idx >> 4;
            int c4 = (idx & 15) * 4;
            int m  = m0 + r;
            float4 v = make_float4(0.f, 0.f, 0.f, 0.f);
            if (m < N_NODES)
                v = *(const float4*)&X[((size_t)b * N_NODES + m) * DIM + c4];
            bf16x4pk pk;
            pk.v[0] = (bf16)v.x; pk.v[1] = (bf16)v.y;
            pk.v[2] = (bf16)v.z; pk.v[3] = (bf16)v.w;
            if (m < N_NODES)
                *(bf16x4pk*)&Xbf[((size_t)b * N_NODES + m) * DIM + c4] = pk;
            T[c4 + 0][r] = pk.v[0];
            T[c4 + 1][r] = pk.v[1];
            T[c4 + 2][r] = pk.v[2];
            T[c4 + 3][r] = pk.v[3];
        }
        __syncthreads();
#pragma unroll
        for (int i = 0; i < 2; ++i) {
            int idx = i * 256 + tid;
            int c   = idx >> 3;
            int mch = idx & 7;
            int kb  = (m0 >> 5) + (mch >> 2);
            if (kb < KB) {
                int q = mch & 3;
                bf16x8 vv = *(const bf16x8*)&T[c][mch * 8];
                *(bf16x8*)&Xtp[((size_t)(b * KB3 + kb) * 256 + q * 64 + c) * 8] = vv;
            }
        }
    } else {
        // ----- wpT2 / embp pack + zero-fill Sp slabs 63..65 -----
        int idx = (bid - N_NODES - 1024) * 256 + tid;
        if (idx < Z0) {
            int col = idx >> 5, d = idx & 31;
            int o  = col / KI;
            int kk = col - o * KI;
            int cheb = kk >> 6, i = kk & 63;
            float v = (d < EMB) ? wp[(((d * 3 + cheb) * 64 + i) * 64) + o] : 0.0f;
            wpT2[idx] = (bf16)v;
        } else if (idx < Z1) {
            int j = idx - Z0;
            int n = j >> 5, d = j & 31;
            float v = (d < EMB) ? emb[n * EMB + d] : 0.0f;
            embp[j] = (bf16)v;
        } else if (idx < Z2) {
            Sp63[idx - Z1] = (bf16)0.0f;
        }
    }
}

// ---------------------------------------------------------------------------
// Kernel 3: spmm — R10's proven structure (double-buffered 3-kb stages,
// 128n x 64c block, 4 waves of 32n x 64c, 2 blocks/CU) + XCD-aware swizzle:
// XCD k (= blockid % 8) owns an 8x8 (ntB x b) sub-grid, so every A- and
// B-slab is fetched once per XCD and L2-shared 8-way (R12 FETCH showed
// B-slabs were fetched from HBM by up to 8 XCDs).
// ---------------------------------------------------------------------------
__global__ __launch_bounds__(256, 2) void spmm_pack(
    const bf16* __restrict__ Ap, const bf16* __restrict__ Btp,
    bf16* __restrict__ Ybf, bf16* __restrict__ Ytp, int write_ytp)
{
    const int i = blockIdx.x;            // 0..511
    const int kx = i & 7, j = i >> 3;    // kx = XCD (dispatch round-robin)
    const int ntB = (j & 7) + 8 * (kx & 1);
    const int b   = ((j >> 3) << 2) + (kx >> 1);
    const int n0  = ntB * 128;
    const int tid = threadIdx.x;
    const int lane = tid & 63, wave = tid >> 6;
    const int l15 = lane & 15, quad = lane >> 4;

    __shared__ bf16 As[2][3 * 4096];   // 24 KB per buffer (128 rows x 3x32 k)
    __shared__ bf16 Bs[2][3 * 2048];   // 12 KB per buffer ( 64 cols x 3x32 k)

    const bf16* aslab = Ap  + (size_t)(ntB * 2) * 2048 + tid * 8;  // + kb*65536
    const bf16* bslab = Btp + (size_t)(b * KB3) * 2048 + tid * 8;  // + kb*2048

#define DMA_STAGE(buf, kb0_) {                                        \
        _Pragma("unroll")                                             \
        for (int jj = 0; jj < 3; ++jj) {                              \
            const bf16* pa = aslab + (size_t)(kb0_ + jj) * (32 * 2048);\
            const bf16* pb = bslab + (size_t)(kb0_ + jj) * 2048;      \
            gl_lds16(pa,        &As[buf][jj * 4096 + tid * 8]);       \
            gl_lds16(pa + 2048, &As[buf][jj * 4096 + 2048 + tid * 8]);\
            gl_lds16(pb,        &Bs[buf][jj * 2048 + tid * 8]);  } }

    f32x4 acc[2][4] = {};
    const int ga = (wave >> 1) * 256 + quad * 64 + (wave & 1) * 32; // A granule base
    const int gb = quad * 64;                                       // B granule base

    DMA_STAGE(0, 0);
#pragma unroll 1
    for (int s = 0; s < 22; ++s) {
        const int cur = s & 1;
        __syncthreads();               // drains vmcnt(0): buf[cur] ready
        bf16x8 af[3][2], bfr[3][4];
#pragma unroll
        for (int jj = 0; jj < 3; ++jj) {
#pragma unroll
            for (int t = 0; t < 2; ++t)
                af[jj][t]  = *(const bf16x8*)&As[cur][jj * 4096 + (ga + t * 16 + l15) * 8];
#pragma unroll
            for (int t = 0; t < 4; ++t)
                bfr[jj][t] = *(const bf16x8*)&Bs[cur][jj * 2048 + (gb + t * 16 + l15) * 8];
        }
        if (s + 1 < 22) DMA_STAGE(cur ^ 1, (s + 1) * 3);
#pragma unroll
        for (int jj = 0; jj < 3; ++jj)
#pragma unroll
            for (int rt = 0; rt < 2; ++rt)
#pragma unroll
                for (int ct = 0; ct < 4; ++ct)
                    acc[rt][ct] = __builtin_amdgcn_mfma_f32_16x16x32_bf16(
                        af[jj][rt], bfr[jj][ct], acc[rt][ct], 0, 0, 0);
    }
#undef DMA_STAGE

    // Epilogue. C/D layout: col = lane&15, row = quad*4 + reg
#pragma unroll
    for (int rt = 0; rt < 2; ++rt) {
        const int nbase = n0 + wave * 32 + rt * 16 + quad * 4;
#pragma unroll
        for (int ct = 0; ct < 4; ++ct) {
            const int c = ct * 16 + l15;
#pragma unroll
            for (int r = 0; r < 4; ++r) {
                int n = nbase + r;
                if (n < N_NODES)
                    Ybf[((size_t)b * N_NODES + n) * DIM + c] = (bf16)acc[rt][ct][r];
            }
            if (write_ytp && nbase + 4 <= N_NODES) {
                const int kb2 = nbase >> 5;
                const int kq  = (nbase & 31) >> 3;
                const int j4  = nbase & 7;       // 0 or 4
                bf16x4pk pk;
                pk.v[0] = (bf16)acc[rt][ct][0];
                pk.v[1] = (bf16)acc[rt][ct][1];
                pk.v[2] = (bf16)acc[rt][ct][2];
                pk.v[3] = (bf16)acc[rt][ct][3];
                *(bf16x4pk*)&Ytp[((size_t)(b * KB3 + kb2) * 256 + kq * 64 + c) * 8 + j4] = pk;
            }
        }
    }
}

// ---------------------------------------------------------------------------
// Kernel 4b: W[n][col] = sum_d embp[n][d] * wpT2[col][d]  (bf16 out)
// ---------------------------------------------------------------------------
__global__ __launch_bounds__(256) void prep_W_mfma(
    const bf16* __restrict__ embp, const bf16* __restrict__ wpT2,
    bf16* __restrict__ W)
{
    const int colbase = blockIdx.x * 256;
    const int n0      = blockIdx.y * 16;
    const int tid  = threadIdx.x;
    const int lane = tid & 63, wave = tid >> 6;
    const int l15 = lane & 15, quad = lane >> 4;

    __shared__ bf16 Cs[16][264];

    const bf16x8 af = *(const bf16x8*)&embp[(n0 + l15) * 32 + quad * 8];
    const f32x4 zero = {};
#pragma unroll
    for (int ct = 0; ct < 4; ++ct) {
        const int col = colbase + wave * 64 + ct * 16 + l15;
        bf16x8 bfr = *(const bf16x8*)&wpT2[(size_t)col * 32 + quad * 8];
        f32x4 acc = __builtin_amdgcn_mfma_f32_16x16x32_bf16(af, bfr, zero, 0, 0, 0);
#pragma unroll
        for (int r = 0; r < 4; ++r)
            Cs[quad * 4 + r][wave * 64 + ct * 16 + l15] = (bf16)acc[r];
    }
    __syncthreads();
    {
        const int row = tid >> 4;
        const int c16 = (tid & 15) * 16;
        bf16x8 v0 = *(const bf16x8*)&Cs[row][c16];
        bf16x8 v1 = *(const bf16x8*)&Cs[row][c16 + 8];
        bf16* dst = &W[(size_t)(n0 + row) * WCOLS + colbase + c16];
        *(bf16x8*)dst       = v0;
        *(bf16x8*)(dst + 8) = v1;
    }
}

// ---------------------------------------------------------------------------
// Kernel 5: per-node combine (bf16 inputs).
// ---------------------------------------------------------------------------
__global__ __launch_bounds__(256) void combine_node(
    const bf16* __restrict__ xbf, const bf16* __restrict__ y1bf,
    const bf16* __restrict__ y2bf, const float* __restrict__ emb,
    const float* __restrict__ bp, const bf16* __restrict__ W,
    float* __restrict__ out)
{
    const int n   = blockIdx.x;
    const int tid = threadIdx.x;
    const int lane = tid & 63, wave = tid >> 6;
    const int l15 = lane & 15, quad = lane >> 4;

    __shared__ bf16 As[BATCH][200];
    __shared__ bf16 Ws[DIM][200];
    __shared__ float bias_s[DIM];
    __shared__ float emb_s[EMB];

    if (tid < EMB) emb_s[tid] = emb[n * EMB + tid];

    {
        const int b  = tid >> 3;
        const int c8 = (tid & 7) * 8;
        const size_t base = ((size_t)b * N_NODES + n) * DIM + c8;
        bf16x8 vx = *(const bf16x8*)&xbf [base];
        bf16x8 v1 = *(const bf16x8*)&y1bf[base];
        bf16x8 v2 = *(const bf16x8*)&y2bf[base];
        bf16x8 p2;
#pragma unroll
        for (int e = 0; e < 8; ++e)
            p2[e] = (bf16)(2.0f * (float)v2[e] - (float)vx[e]);
        *(bf16x8*)&As[b][c8]       = vx;
        *(bf16x8*)&As[b][64 + c8]  = v1;
        *(bf16x8*)&As[b][128 + c8] = p2;
    }
    {
        const bf16* Wn = W + (size_t)n * WCOLS;
#pragma unroll
        for (int jj = 0; jj < 6; ++jj) {
            int chunk = jj * 256 + tid;
            int o  = chunk / 24;
            int kc = chunk - o * 24;
            bf16x8 v = *(const bf16x8*)&Wn[(size_t)chunk * 8];
            *(bf16x8*)&Ws[o][kc * 8] = v;
        }
    }
    __syncthreads();

    if (tid < DIM) {
        float s = 0.0f;
#pragma unroll
        for (int d = 0; d < EMB; ++d) s += emb_s[d] * bp[d * DIM + tid];
        bias_s[tid] = s;
    }

    bf16x8 af[2][6];
#pragma unroll
    for (int mt = 0; mt < 2; ++mt)
#pragma unroll
        for (int ks = 0; ks < 6; ++ks)
            af[mt][ks] = *(const bf16x8*)&As[mt * 16 + l15][ks * 32 + quad * 8];

    f32x4 acc[2] = {};
#pragma unroll
    for (int ks = 0; ks < 6; ++ks) {
        bf16x8 bfr = *(const bf16x8*)&Ws[wave * 16 + l15][ks * 32 + quad * 8];
        acc[0] = __builtin_amdgcn_mfma_f32_16x16x32_bf16(af[0][ks], bfr, acc[0], 0, 0, 0);
        acc[1] = __builtin_amdgcn_mfma_f32_16x16x32_bf16(af[1][ks], bfr, acc[1], 0, 0, 0);
    }
    __syncthreads();

    const int o = wave * 16 + l15;
    const float bv = bias_s[o];
#pragma unroll
    for (int mt = 0; mt < 2; ++mt)
#pragma unroll
        for (int r = 0; r < 4; ++r) {
            int b = mt * 16 + quad * 4 + r;
            out[((size_t)b * N_NODES + n) * DIM + o] = acc[mt][r] + bv;
        }
}

// ---------------------------------------------------------------------------
extern "C" void kernel_launch(void* const* d_in, const int* in_sizes, int n_in,
                              void* d_out, int out_size, void* d_ws, size_t ws_size,
                              hipStream_t stream) {
    const float* x   = (const float*)d_in[0];  // [32,2000,64]
    const float* emb = (const float*)d_in[1];  // [2000,16]
    const float* nv1 = (const float*)d_in[2];  // [2000,16]
    const float* nv2 = (const float*)d_in[3];  // [16,2000]
    const float* wp  = (const float*)d_in[4];  // [16,3,64,64]
    const float* bp  = (const float*)d_in[5];  // [16,64]
    float* out = (float*)d_out;                // [32,2000,64]

    char* w = (char*)d_ws;
    bf16* Sp   = (bf16*)w;  w += (size_t)KB3 * NP * 32 * 2;           //  8.65 MB
    bf16* xTp  = (bf16*)w;  w += (size_t)BATCH * KB3 * DIM * 32 * 2;  //  8.65 MB
    bf16* y1Tp = (bf16*)w;  w += (size_t)BATCH * KB3 * DIM * 32 * 2;  //  8.65 MB
    bf16* xbf  = (bf16*)w;  w += (size_t)BATCH * N_NODES * DIM * 2;   //  8.19 MB
    bf16* y1bf = (bf16*)w;  w += (size_t)BATCH * N_NODES * DIM * 2;   //  8.19 MB
    bf16* y2bf = (bf16*)w;  w += (size_t)BATCH * N_NODES * DIM * 2;   //  8.19 MB
    bf16* wpT2 = (bf16*)w;  w += (size_t)WCOLS * 32 * 2;              //  0.79 MB
    bf16* embp = (bf16*)w;  w += (size_t)N_NODES * 32 * 2;            //  0.13 MB
    bf16* W    = (bf16*)w;                                            // 49.15 MB

    prep_fused<<<PREP_BLOCKS, 256, 0, stream>>>(
        nv1, nv2, Sp, x, xTp, xbf, wp, emb, wpT2, embp,
        Sp + (size_t)63 * NP * 32);
    prep_W_mfma<<<dim3(WCOLS / 256, N_NODES / 16), 256, 0, stream>>>(embp, wpT2, W);
    spmm_pack<<<512, 256, 0, stream>>>(Sp, xTp,  y1bf, y1Tp, 1);
    spmm_pack<<<512, 256, 0, stream>>>(Sp, y1Tp, y2bf, y1Tp, 0);
    combine_node<<<N_NODES, 256, 0, stream>>>(xbf, y1bf, y2bf, emb, bp, W, out);
}